// Round 8
// baseline (132.958 us; speedup 1.0000x reference)
//
#include <hip/hip_runtime.h>
#include <hip/hip_bf16.h>

#define BATCH 32
#define LL 512
#define DD 768
#define EPSC 1e-5f

typedef __attribute__((ext_vector_type(8))) short bf16x8;
typedef __attribute__((ext_vector_type(4))) float f32x4;

// ---------------------------------------------------------------------------
// Kernel 1 (fused prep): block = (l-block of 64 rows, batch). Phase 1 computes
// w[l] = (eps + sum_d x^2)^(1/4) in-register (4 lanes per row, 2 shfl).
// Phase 2 = the harness-verified 64x64 LDS transpose body, iterated over the
// 12 d-tiles (x re-reads come from L2). ~12 us = its 75 MB HBM floor.
// ---------------------------------------------------------------------------
__global__ __launch_bounds__(256) void k_prep(const float* __restrict__ x,
                                              ushort* __restrict__ yt) {
    __shared__ float tile[64][65];
    __shared__ float svec[64];
    int lb = blockIdx.x;                              // [0,8) l-block
    int b = blockIdx.y;
    int l0 = lb * 64;
    int t = threadIdx.x;

    // Phase 1: row r = t>>2 (0..63), quarter q = t&3 covers 192 floats.
    {
        int r = t >> 2, q = t & 3;
        const float4* xr = (const float4*)(x + ((size_t)b * LL + l0 + r) * DD) + q * 48;
        float sum = 0.f;
#pragma unroll 8
        for (int i = 0; i < 48; i++) {
            float4 v = xr[i];
            sum += v.x * v.x + v.y * v.y + v.z * v.z + v.w * v.w;
        }
        sum += __shfl_xor(sum, 1, 64);
        sum += __shfl_xor(sum, 2, 64);
        if (q == 0) svec[r] = sqrtf(sqrtf(EPSC + sum));
    }
    __syncthreads();

    // Phase 2: 12 x (load 64x64 tile -> transpose+scale -> bf16 store).
    const float* xb = x + ((size_t)b * LL + l0) * DD;
    int f = t & 15, lr0 = t >> 4;                     // f: float4 col, lr0: row
    int lc = t & 7, dl0 = t >> 3;                     // lc: l-chunk, dl0: d row
    for (int dt = 0; dt < 12; dt++) {
        int d0 = dt * 64;
#pragma unroll
        for (int r = 0; r < 4; r++) {
            int l = lr0 + r * 16;
            float4 v = *(const float4*)(xb + (size_t)l * DD + d0 + f * 4);
#pragma unroll
            for (int j = 0; j < 4; j++)
                tile[l][f * 4 + j] = ((const float*)&v)[j];
        }
        __syncthreads();
        ushort* yp = yt + ((size_t)b * DD + d0) * LL + l0;
#pragma unroll
        for (int it = 0; it < 2; it++) {
            int d = dl0 + it * 32;
            bf16x8 w;
#pragma unroll
            for (int j = 0; j < 8; j++) {
                int l = lc * 8 + j;
                float v = tile[l][d] * svec[l];
                __hip_bfloat16 h = __float2bfloat16(v);
                w[j] = *(short*)&h;
            }
            *(bf16x8*)(yp + (size_t)d * LL + lc * 8) = w;
        }
        __syncthreads();
    }
}

// ---------------------------------------------------------------------------
// Kernel 2: C[b] = Yt[b]*Yt[b]^T, symmetric. R7's verified single-barrier
// double-buffered BK=64 pipeline, tile 64 -> 128: 4 waves (2x2), each owning
// 64x64 (acc[4][4], all indices compile-time constant -- rule #20). Per
// K-step per wave: 16 ds_read_b128 -> 32 MFMAs (ratio 0.5 vs R7's 1.0) --
// halves the dominant LDS-read term (12.5 -> ~6.7 us aggregate). L2 staging
// 320 -> 172 MB. 8 barriers/block. LDS 64 KB -> 2 blocks/CU (8 waves/CU).
// 672 blocks: 6x6 tile grid, 21 upper-tri pairs x 32 batches; XCD swizzle
// bijective (672 = 8 x 84 = 8 x 4 x 21). Swizzle: physical 16B-chunk c of
// row r holds logical chunk c ^ (r&7); staged via pre-swizzled GLOBAL
// addresses (linear LDS dest), frag reads apply the same XOR (rule #21).
// ---------------------------------------------------------------------------
__global__ __launch_bounds__(256) void k_gemm(const ushort* __restrict__ yt,
                                              float* __restrict__ out) {
    __shared__ ushort At[2][128 * 64];                // 2 x 16 KB
    __shared__ ushort Bt[2][128 * 64];
    int i = blockIdx.x;                               // [0, 672)
    int xcd = i & 7, slot = i >> 3;                   // XCD round-robin
    int b = xcd + 8 * (slot / 21);
    int p = slot % 21;
    int t = p, tm = 0, rem = 6;
    while (t >= rem) { t -= rem; rem--; tm++; }
    int tn = tm + t;                                  // tm <= tn
    bool diag = (tm == tn);
    int m0 = tm * 128, n0 = tn * 128;
    int tid = threadIdx.x;
    int wave = tid >> 6, lane = tid & 63;
    int wr = wave >> 1, wc = wave & 1;                // 2x2 waves, 64x64 each
    const ushort* yb = yt + (size_t)b * DD * LL;

    f32x4 acc[4][4];
#pragma unroll
    for (int ii = 0; ii < 4; ii++)
#pragma unroll
        for (int j = 0; j < 4; j++) acc[ii][j] = (f32x4){0.f, 0.f, 0.f, 0.f};

    // Staging: per matrix per buffer = 128 rows x 8 chunks = 1024 16B-slots;
    // 256 threads -> 4 issues. Slot s = is*256 + tid: row = s>>3, physical
    // chunk = s&7, logical chunk = (s&7) ^ (row&7) (pre-swizzled source).
    int sr[4], sc[4];
#pragma unroll
    for (int is = 0; is < 4; is++) {
        int s = is * 256 + tid;
        sr[is] = s >> 3;
        sc[is] = (s & 7) ^ (sr[is] & 7);
    }
    const ushort* gA[4];
    const ushort* gB[4];
#pragma unroll
    for (int is = 0; is < 4; is++) {
        gA[is] = yb + (size_t)(m0 + sr[is]) * LL + sc[is] * 8;
        gB[is] = yb + (size_t)(n0 + sr[is]) * LL + sc[is] * 8;
    }
    // LDS dest: wave-uniform base + lane*16B (global_load_lds contract).
    int ldsOff[4];
#pragma unroll
    for (int is = 0; is < 4; is++) ldsOff[is] = (is * 256 + wave * 64) * 8;

    // Frag read: lane (fr, ks4); row r chunk h*4+ks4 lives at slot ^(r&7).
    int fr = lane & 15, ks4 = lane >> 4;

#define STAGE(buf, ks) do {                                                   \
        int k0_ = (ks) * 64;                                                  \
        _Pragma("unroll")                                                     \
        for (int is = 0; is < 4; is++)                                        \
            __builtin_amdgcn_global_load_lds(                                 \
                (const __attribute__((address_space(1))) void*)(gA[is] + k0_),\
                (__attribute__((address_space(3))) void*)(At[buf] + ldsOff[is]),\
                16, 0, 0);                                                    \
        if (!diag) {                                                          \
            _Pragma("unroll")                                                 \
            for (int is = 0; is < 4; is++)                                    \
                __builtin_amdgcn_global_load_lds(                             \
                    (const __attribute__((address_space(1))) void*)(gB[is] + k0_),\
                    (__attribute__((address_space(3))) void*)(Bt[buf] + ldsOff[is]),\
                    16, 0, 0);                                                \
        }                                                                     \
    } while (0)

    STAGE(0, 0);
    __syncthreads();                                  // buf0 ready
    for (int ks = 0; ks < 8; ks++) {
        int cur = ks & 1;
        if (ks < 7) STAGE(cur ^ 1, ks + 1);           // prefetch next tile
        const ushort* Ab = At[cur];
        const ushort* Bb = diag ? At[cur] : Bt[cur];
        bf16x8 af[4][2], bf[4][2];
#pragma unroll
        for (int ii = 0; ii < 4; ii++) {
            int mr = wr * 64 + ii * 16 + fr;
            int nr = wc * 64 + ii * 16 + fr;
#pragma unroll
            for (int h = 0; h < 2; h++) {
                int slm = ((h * 4 + ks4) ^ (mr & 7)) * 8;
                int sln = ((h * 4 + ks4) ^ (nr & 7)) * 8;
                af[ii][h] = *(const bf16x8*)(Ab + mr * 64 + slm);
                bf[ii][h] = *(const bf16x8*)(Bb + nr * 64 + sln);
            }
        }
#pragma unroll
        for (int ii = 0; ii < 4; ii++)
#pragma unroll
            for (int j = 0; j < 4; j++)
#pragma unroll
                for (int h = 0; h < 2; h++)
                    acc[ii][j] = __builtin_amdgcn_mfma_f32_16x16x32_bf16(
                        af[ii][h], bf[j][h], acc[ii][j], 0, 0, 0);
        if (ks < 7) __syncthreads();                  // drain stage + handoff
    }
#undef STAGE

    // Epilogue. C/D layout: col = lane&15, row = (lane>>4)*4 + r.
    // Mirror (transposed) write is float4; direct write scalar (off-diag).
    float* op = out + (size_t)b * DD * DD;
#pragma unroll
    for (int ii = 0; ii < 4; ii++) {
        int colb = m0 + wr * 64 + ii * 16 + ks4 * 4;
#pragma unroll
        for (int j = 0; j < 4; j++) {
            int row = n0 + wc * 64 + j * 16 + fr;
            float4 v = {acc[ii][j][0], acc[ii][j][1], acc[ii][j][2], acc[ii][j][3]};
            *(float4*)(op + (size_t)row * DD + colb) = v;   // mirror (or diag)
        }
    }
    if (!diag) {
#pragma unroll
        for (int ii = 0; ii < 4; ii++) {
            int mbase = m0 + wr * 64 + ii * 16 + ks4 * 4;
#pragma unroll
            for (int j = 0; j < 4; j++) {
                int n = n0 + wc * 64 + j * 16 + fr;
#pragma unroll
                for (int r = 0; r < 4; r++)
                    op[(size_t)(mbase + r) * DD + n] = acc[ii][j][r];
            }
        }
    }
}

// ---------------------------------------------------------------------------
extern "C" void kernel_launch(void* const* d_in, const int* in_sizes, int n_in,
                              void* d_out, int out_size, void* d_ws, size_t ws_size,
                              hipStream_t stream) {
    const float* x = (const float*)d_in[0];
    ushort* yt = (ushort*)d_ws;                                     // 25.2 MB bf16

    k_prep<<<dim3(LL / 64, BATCH), 256, 0, stream>>>(x, yt);
    k_gemm<<<dim3(21 * BATCH), 256, 0, stream>>>(yt, (float*)d_out);
}